// Round 1
// baseline (10686.129 us; speedup 1.0000x reference)
//
#include <hip/hip_runtime.h>
#include <cmath>

#define VOCAB 20000
#define EMB 300
#define FEAT 2052
#define HID 1024
#define OUTN 3000
#define NK 8
#define NS 10
#define KOBJ 36
#define BATCH 256
#define QLEN_ 14

// ---------------- universal tiled fp32 GEMM ----------------
// C[M,N] = op: A(M,K,lda) @ B, B either (N,K,ldb) row-major (TRANSB=x@W^T) or (K,N,ldb).
// epilogue: v = acc (+ C if beta) (+ bias[n]) ; relu ; * mul[m,n]
#define TM 64
#define TN 64
#define TK 16

template<bool TRANSB>
__global__ __launch_bounds__(256)
void gemm_k(const float* __restrict__ A, int lda,
            const float* __restrict__ B, int ldb,
            float* __restrict__ C, int ldc,
            const float* __restrict__ bias,
            const float* __restrict__ mul, int ldmul,
            int M, int N, int K, int beta, int relu)
{
    __shared__ float As[TK][TM + 1];
    __shared__ float Bs[TK][TN + 1];
    int tx = threadIdx.x, ty = threadIdx.y;
    int tid = ty * 16 + tx;
    int m0 = blockIdx.y * TM;
    int n0 = blockIdx.x * TN;
    float acc[4][4] = {};
    for (int k0 = 0; k0 < K; k0 += TK) {
        { // A tile
            int mm = tid >> 2;
            int kk = (tid & 3) * 4;
            int m = m0 + mm;
            #pragma unroll
            for (int j = 0; j < 4; j++) {
                int k = k0 + kk + j;
                As[kk + j][mm] = (m < M && k < K) ? A[(size_t)m * lda + k] : 0.f;
            }
        }
        if constexpr (TRANSB) {
            int nn = tid >> 2;
            int kk = (tid & 3) * 4;
            int n = n0 + nn;
            #pragma unroll
            for (int j = 0; j < 4; j++) {
                int k = k0 + kk + j;
                Bs[kk + j][nn] = (n < N && k < K) ? B[(size_t)n * ldb + k] : 0.f;
            }
        } else {
            int kk = tid >> 4;
            int nn = (tid & 15) * 4;
            int k = k0 + kk;
            #pragma unroll
            for (int j = 0; j < 4; j++) {
                int n = n0 + nn + j;
                Bs[kk][nn + j] = (k < K && n < N) ? B[(size_t)k * ldb + n] : 0.f;
            }
        }
        __syncthreads();
        #pragma unroll
        for (int kk = 0; kk < TK; kk++) {
            float a[4], b[4];
            #pragma unroll
            for (int i = 0; i < 4; i++) a[i] = As[kk][ty + i * 16];
            #pragma unroll
            for (int j = 0; j < 4; j++) b[j] = Bs[kk][tx + j * 16];
            #pragma unroll
            for (int i = 0; i < 4; i++)
                #pragma unroll
                for (int j = 0; j < 4; j++)
                    acc[i][j] += a[i] * b[j];
        }
        __syncthreads();
    }
    #pragma unroll
    for (int i = 0; i < 4; i++) {
        int m = m0 + ty + i * 16;
        if (m >= M) continue;
        #pragma unroll
        for (int j = 0; j < 4; j++) {
            int n = n0 + tx + j * 16;
            if (n >= N) continue;
            float v = acc[i][j];
            if (beta) v += C[(size_t)m * ldc + n];
            if (bias) v += bias[n];
            if (relu) v = fmaxf(v, 0.f);
            if (mul)  v *= mul[(size_t)m * ldmul + n];
            C[(size_t)m * ldc + n] = v;
        }
    }
}

static void gemm(hipStream_t s, const float* A, int lda, const float* B, int ldb, bool transB,
                 float* C, int ldc, const float* bias, const float* mul, int ldmul,
                 int M, int N, int K, int beta, int relu)
{
    dim3 grid((N + TN - 1) / TN, (M + TM - 1) / TM);
    dim3 blk(16, 16);
    if (transB) gemm_k<true ><<<grid, blk, 0, s>>>(A, lda, B, ldb, C, ldc, bias, mul, ldmul, M, N, K, beta, relu);
    else        gemm_k<false><<<grid, blk, 0, s>>>(A, lda, B, ldb, C, ldc, bias, mul, ldmul, M, N, K, beta, relu);
}

// ---------------- small kernels ----------------
__global__ void fill0_k(float* p, int n) {
    int i = blockIdx.x * 256 + threadIdx.x;
    if (i < n) p[i] = 0.f;
}

__global__ void embed_k(const int* __restrict__ q, const float* __restrict__ wemb, float* __restrict__ emb) {
    int i = blockIdx.x * 256 + threadIdx.x;
    if (i >= BATCH * QLEN_ * EMB) return;
    int e = i % EMB; int bt = i / EMB;
    emb[i] = wemb[(size_t)q[bt] * EMB + e];
}

__global__ void gru_point_k(const float* __restrict__ gi, const float* __restrict__ gh,
                            const int* __restrict__ qlen, float* __restrict__ h, int t) {
    int i = blockIdx.x * 256 + threadIdx.x;
    if (i >= BATCH * HID) return;
    int b = i / HID; int j = i % HID;
    float ir = gi[(size_t)b * 3 * HID + j];
    float iz = gi[(size_t)b * 3 * HID + HID + j];
    float in = gi[(size_t)b * 3 * HID + 2 * HID + j];
    float hr = gh[(size_t)b * 3 * HID + j];
    float hz = gh[(size_t)b * 3 * HID + HID + j];
    float hn = gh[(size_t)b * 3 * HID + 2 * HID + j];
    float r = 1.f / (1.f + expf(-(ir + hr)));
    float z = 1.f / (1.f + expf(-(iz + hz)));
    float n = tanhf(in + r * hn);
    float hold = h[i];
    float hnew = (1.f - z) * n + z * hold;
    h[i] = (t < qlen[b]) ? hnew : hold;
}

// raw[b,l] = sum_h proj[b*L+l][h]*qproj[b][h]*attw[h] + attb   (one wave per row)
__global__ __launch_bounds__(256)
void attraw_k(const float* __restrict__ proj, const float* __restrict__ qproj,
              const float* __restrict__ attw, const float* __restrict__ attb,
              float* __restrict__ raw, int L) {
    int wave = blockIdx.x * 4 + (threadIdx.x >> 6);
    int lane = threadIdx.x & 63;
    if (wave >= BATCH * L) return;
    int b = wave / L;
    const float* p = proj + (size_t)wave * HID;
    const float* q = qproj + (size_t)b * HID;
    float s = 0.f;
    for (int hh = lane; hh < HID; hh += 64) s += p[hh] * q[hh] * attw[hh];
    #pragma unroll
    for (int o = 32; o; o >>= 1) s += __shfl_down(s, o, 64);
    if (lane == 0) raw[wave] = s + attb[0];
}

__global__ void softmax_k(float* raw, int L) {
    int b = blockIdx.x * blockDim.x + threadIdx.x;
    if (b >= BATCH) return;
    float* r = raw + (size_t)b * L;
    float mx = -1e30f;
    for (int l = 0; l < L; l++) mx = fmaxf(mx, r[l]);
    float sum = 0.f;
    for (int l = 0; l < L; l++) { float e = expf(r[l] - mx); r[l] = e; sum += e; }
    float inv = 1.f / sum;
    for (int l = 0; l < L; l++) r[l] *= inv;
}

// out[b, out_off + f] = sum_l src[(b*L+l)*F + f] * att[b*L+l]
__global__ void wsum_k(const float* __restrict__ src, const float* __restrict__ att,
                       float* __restrict__ out, int L, int F, int out_ld, int out_off) {
    int i = blockIdx.x * 256 + threadIdx.x;
    if (i >= BATCH * F) return;
    int b = i / F, f = i % F;
    float s = 0.f;
    for (int l = 0; l < L; l++) s += src[((size_t)b * L + l) * F + f] * att[b * L + l];
    out[(size_t)b * out_ld + out_off + f] = s;
}

// jax.lax.top_k: descending, ties -> lowest index (strict > selection sort matches)
__global__ void topk_k(const float* __restrict__ att, int* __restrict__ idx) {
    int b = blockIdx.x * blockDim.x + threadIdx.x;
    if (b >= BATCH) return;
    float v[KOBJ]; bool taken[KOBJ];
    for (int l = 0; l < KOBJ; l++) { v[l] = att[(size_t)b * KOBJ + l]; taken[l] = false; }
    for (int s = 0; s < NS; s++) {
        float best = -1e30f; int bi = 0;
        for (int l = 0; l < KOBJ; l++)
            if (!taken[l] && v[l] > best) { best = v[l]; bi = l; }
        taken[bi] = true;
        idx[b * NS + s] = bi;
    }
}

__global__ void gather_k(const float* __restrict__ img, const int* __restrict__ idx, float* __restrict__ out) {
    int i = blockIdx.x * 256 + threadIdx.x;
    if (i >= BATCH * NS * FEAT) return;
    int f = i % FEAT; int bs = i / FEAT; int b = bs / NS; int s = bs % NS;
    out[i] = img[((size_t)b * KOBJ + idx[b * NS + s]) * FEAT + f];
}

// pseudo (rho,theta) from bb centres + both Gaussian kernel weight sets
__global__ void kw_k(const float* __restrict__ timg,
                     const float* __restrict__ mu1, const float* __restrict__ sig1,
                     const float* __restrict__ mu2, const float* __restrict__ sig2,
                     float* __restrict__ kw1, float* __restrict__ kw2) {
    int i = blockIdx.x * blockDim.x + threadIdx.x; // over B*NS*NS
    if (i >= BATCH * NS * NS) return;
    int m = i % NS; int bn = i / NS; int b = bn / NS; int n = bn % NS;
    const float* bbn = timg + ((size_t)(b * NS + n)) * FEAT + (FEAT - 4);
    const float* bbm = timg + ((size_t)(b * NS + m)) * FEAT + (FEAT - 4);
    float cnx = bbn[0] + 0.5f * (bbn[2] - bbn[0]);
    float cny = bbn[1] + 0.5f * (bbn[3] - bbn[1]);
    float cmx = bbm[0] + 0.5f * (bbm[2] - bbm[0]);
    float cmy = bbm[1] + 0.5f * (bbm[3] - bbm[1]);
    float d0 = cnx - cmx, d1 = cny - cmy;
    float rho = sqrtf(d0 * d0 + d1 * d1);
    float theta = atan2f(d0, d1);   // arctan2(d0, d1) as in reference
    #pragma unroll
    for (int k = 0; k < NK; k++) {
        float a1 = (rho   - mu1[k * 2 + 0]) / (1e-14f + sig1[k * 2 + 0]);
        float b1 = (theta - mu1[k * 2 + 1]) / (1e-14f + sig1[k * 2 + 1]);
        kw1[(size_t)i * NK + k] = expf(-0.5f * (a1 * a1 + b1 * b1));
        float a2 = (rho   - mu2[k * 2 + 0]) / (1e-14f + sig2[k * 2 + 0]);
        float b2 = (theta - mu2[k * 2 + 1]) / (1e-14f + sig2[k * 2 + 1]);
        kw2[(size_t)i * NK + k] = expf(-0.5f * (a2 * a2 + b2 * b2));
    }
}

// out[(b*NS+n)*CT + c] = relu(bias[c] + sum_m kw[((b*NS+n)*NS+m)*NK + k] * Y[(b*NS+m)*CT + c]), k = c/KO
__global__ void mix_k(const float* __restrict__ Y, const float* __restrict__ kw,
                      const float* __restrict__ bias, float* __restrict__ out,
                      int KO, int CT) {
    int i = blockIdx.x * blockDim.x + threadIdx.x;
    if (i >= BATCH * NS * CT) return;
    int c = i % CT; int bn = i / CT; int b = bn / NS;
    int k = c / KO;
    float s = bias[c];
    const float* kwp = kw + ((size_t)bn * NS) * NK + k;
    const float* Yp  = Y + ((size_t)b * NS) * CT + c;
    #pragma unroll
    for (int m = 0; m < NS; m++) s += kwp[m * NK] * Yp[(size_t)m * CT];
    out[i] = fmaxf(s, 0.f);
}

// ---------------- launch ----------------
extern "C" void kernel_launch(void* const* d_in, const int* in_sizes, int n_in,
                              void* d_out, int out_size, void* d_ws, size_t ws_size,
                              hipStream_t stream)
{
    const int*   question  = (const int*)d_in[0];
    const float* image     = (const float*)d_in[1];
    const int*   qlen      = (const int*)d_in[3];
    const float* wembed    = (const float*)d_in[4];
    const float* gru_wih   = (const float*)d_in[5];
    const float* gru_whh   = (const float*)d_in[6];
    const float* gru_bih   = (const float*)d_in[7];
    const float* gru_bhh   = (const float*)d_in[8];
    const float* ia_img_w  = (const float*)d_in[9];
    const float* ia_img_b  = (const float*)d_in[10];
    const float* ia_txt_w  = (const float*)d_in[11];
    const float* ia_txt_b  = (const float*)d_in[12];
    const float* ia_att_w  = (const float*)d_in[13];
    const float* ia_att_b  = (const float*)d_in[14];
    const float* ga_img_w  = (const float*)d_in[15];
    const float* ga_img_b  = (const float*)d_in[16];
    const float* ga_txt_w  = (const float*)d_in[17];
    const float* ga_txt_b  = (const float*)d_in[18];
    const float* ga_att_w  = (const float*)d_in[19];
    const float* ga_att_b  = (const float*)d_in[20];
    const float* gc1_mu    = (const float*)d_in[21];
    const float* gc1_sigma = (const float*)d_in[22];
    const float* gc1_w     = (const float*)d_in[23];
    const float* gc1_b     = (const float*)d_in[24];
    const float* gc2_mu    = (const float*)d_in[25];
    const float* gc2_sigma = (const float*)d_in[26];
    const float* gc2_w     = (const float*)d_in[27];
    const float* gc2_b     = (const float*)d_in[28];
    const float* out1_w    = (const float*)d_in[29];
    const float* out1_b    = (const float*)d_in[30];
    const float* out2_w    = (const float*)d_in[31];
    const float* out2_b    = (const float*)d_in[32];
    const float* iout1_w   = (const float*)d_in[33];
    const float* iout1_b   = (const float*)d_in[34];
    const float* iout2_w   = (const float*)d_in[35];
    const float* iout2_b   = (const float*)d_in[36];
    float* out = (float*)d_out;

    // ---- workspace layout (floats) ----
    float* ws = (float*)d_ws;
    size_t off = 0;
    auto alloc = [&](size_t n) { size_t o = off; off += (n + 63) & ~(size_t)63; return ws + o; };
    float* qenc   = alloc((size_t)BATCH * HID);            // GRU h, persists as qenc
    float* icomb  = alloc((size_t)BATCH * HID);            // img_ques_comb
    float* gcomb  = alloc((size_t)BATCH * HID);            // graph_ques_comb
    float* att_ia = alloc((size_t)BATCH * KOBJ);
    float* att_ga = alloc((size_t)BATCH * NS);
    int*   tidx   = (int*)alloc((size_t)BATCH * NS);
    float* timg   = alloc((size_t)BATCH * NS * FEAT);      // topk_img
    float* kw1    = alloc((size_t)BATCH * NS * NS * NK);
    float* kw2    = alloc((size_t)BATCH * NS * NS * NK);
    float* h1     = alloc((size_t)BATCH * NS * 2 * HID);
    float* h2     = alloc((size_t)BATCH * NS * HID);
    float* scr    = alloc((size_t)10224640);               // phase-reused scratch

    // ===== Phase A: GRU encoder =====
    fill0_k<<<(BATCH * HID + 255) / 256, 256, 0, stream>>>(qenc, BATCH * HID);
    float* emb = scr;                   // 1,075,200
    float* gi  = scr + 1075200;         // 786,432
    float* gh  = gi + 786432;           // 786,432
    embed_k<<<(BATCH * QLEN_ * EMB + 255) / 256, 256, 0, stream>>>(question, wembed, emb);
    for (int t = 0; t < QLEN_; t++) {
        gemm(stream, emb + t * EMB, QLEN_ * EMB, gru_wih, EMB, true, gi, 3 * HID,
             gru_bih, nullptr, 0, BATCH, 3 * HID, EMB, 0, 0);
        gemm(stream, qenc, HID, gru_whh, HID, true, gh, 3 * HID,
             gru_bhh, nullptr, 0, BATCH, 3 * HID, HID, 0, 0);
        gru_point_k<<<(BATCH * HID + 255) / 256, 256, 0, stream>>>(gi, gh, qlen, qenc, t);
    }

    // ===== Phase B: image attention =====
    float* improj = scr;                 // 9,437,184
    float* qproj  = scr + 9437184;       // 262,144
    float* imatt  = qproj + 262144;      // 525,312
    gemm(stream, image, FEAT, ia_img_w, FEAT, true, improj, HID,
         ia_img_b, nullptr, 0, BATCH * KOBJ, HID, FEAT, 0, 1);
    gemm(stream, qenc, HID, ia_txt_w, HID, true, qproj, HID,
         ia_txt_b, nullptr, 0, BATCH, HID, HID, 0, 1);
    attraw_k<<<(BATCH * KOBJ) / 4, 256, 0, stream>>>(improj, qproj, ia_att_w, ia_att_b, att_ia, KOBJ);
    softmax_k<<<1, 256, 0, stream>>>(att_ia, KOBJ);
    wsum_k<<<(BATCH * FEAT + 255) / 256, 256, 0, stream>>>(image, att_ia, imatt, KOBJ, FEAT, FEAT, 0);
    gemm(stream, imatt, FEAT, ia_img_w, FEAT, true, icomb, HID,
         ia_img_b, qproj, HID, BATCH, HID, FEAT, 0, 1);   // relu(...) * q_proj

    // ===== Phase C: top-k + graph convs =====
    topk_k<<<1, 256, 0, stream>>>(att_ia, tidx);
    gather_k<<<(BATCH * NS * FEAT + 255) / 256, 256, 0, stream>>>(image, tidx, timg);
    kw_k<<<(BATCH * NS * NS + 255) / 256, 256, 0, stream>>>(timg, gc1_mu, gc1_sigma, gc2_mu, gc2_sigma, kw1, kw2);
    float* Y1 = scr;                     // 5,242,880
    float* Y2 = scr + 5242880;           // 2,621,440
    // gc1: Y1[b,m,k,o] = sum_f timg[b,m,f] * w1[k,f,o]; then mix over m with kw1
    for (int k = 0; k < NK; k++)
        gemm(stream, timg, FEAT, gc1_w + (size_t)k * FEAT * 256, 256, false,
             Y1 + k * 256, 2 * HID, nullptr, nullptr, 0, BATCH * NS, 256, FEAT, 0, 0);
    mix_k<<<(BATCH * NS * 2 * HID + 255) / 256, 256, 0, stream>>>(Y1, kw1, gc1_b, h1, 256, 2 * HID);
    // gc2
    for (int k = 0; k < NK; k++)
        gemm(stream, h1, 2 * HID, gc2_w + (size_t)k * 2 * HID * 128, 128, false,
             Y2 + k * 128, HID, nullptr, nullptr, 0, BATCH * NS, 128, 2 * HID, 0, 0);
    mix_k<<<(BATCH * NS * HID + 255) / 256, 256, 0, stream>>>(Y2, kw2, gc2_b, h2, 128, HID);

    // ===== Phase D: graph attention (graph_nodes = [timg | h2], never materialized) =====
    float* gproj  = scr;                 // 2,621,440
    float* qproj2 = scr + 2621440;       // 262,144
    float* gatt_i = qproj2 + 262144;     // 787,456 (B x 3076)
    gemm(stream, timg, FEAT, ga_img_w, FEAT + HID, true, gproj, HID,
         nullptr, nullptr, 0, BATCH * NS, HID, FEAT, 0, 0);
    gemm(stream, h2, HID, ga_img_w + FEAT, FEAT + HID, true, gproj, HID,
         ga_img_b, nullptr, 0, BATCH * NS, HID, HID, 1, 1);
    gemm(stream, qenc, HID, ga_txt_w, HID, true, qproj2, HID,
         ga_txt_b, nullptr, 0, BATCH, HID, HID, 0, 1);
    attraw_k<<<(BATCH * NS) / 4, 256, 0, stream>>>(gproj, qproj2, ga_att_w, ga_att_b, att_ga, NS);
    softmax_k<<<1, 256, 0, stream>>>(att_ga, NS);
    wsum_k<<<(BATCH * FEAT + 255) / 256, 256, 0, stream>>>(timg, att_ga, gatt_i, NS, FEAT, FEAT + HID, 0);
    wsum_k<<<(BATCH * HID + 255) / 256, 256, 0, stream>>>(h2, att_ga, gatt_i, NS, HID, FEAT + HID, FEAT);
    gemm(stream, gatt_i, FEAT + HID, ga_img_w, FEAT + HID, true, gcomb, HID,
         ga_img_b, qproj2, HID, BATCH, HID, FEAT + HID, 0, 1);

    // ===== Phase E: output MLPs =====
    float* hid1 = scr;
    float* hid2 = scr + 768000;
    gemm(stream, gcomb, HID, out1_w, HID, true, hid1, OUTN,
         out1_b, nullptr, 0, BATCH, OUTN, HID, 0, 1);
    gemm(stream, icomb, HID, iout1_w, HID, true, hid2, OUTN,
         iout1_b, nullptr, 0, BATCH, OUTN, HID, 0, 1);
    gemm(stream, hid1, OUTN, out2_w, OUTN, true, out, OUTN,
         out2_b, nullptr, 0, BATCH, OUTN, OUTN, 0, 0);
    gemm(stream, hid2, OUTN, iout2_w, OUTN, true, out, OUTN,
         iout2_b, nullptr, 0, BATCH, OUTN, OUTN, 1, 0);
}

// Round 2
// 3557.101 us; speedup vs baseline: 3.0042x; 3.0042x over previous
//
#include <hip/hip_runtime.h>
#include <cmath>

#define VOCAB 20000
#define EMB 300
#define FEAT 2052
#define HID 1024
#define OUTN 3000
#define NK 8
#define NS 10
#define KOBJ 36
#define BATCH 256
#define QLEN_ 14

typedef __attribute__((ext_vector_type(8))) short bf8v;
typedef __attribute__((ext_vector_type(4))) float f4v;

__device__ __forceinline__ short f2bf(float f) {
    union { float f; unsigned u; } v; v.f = f;
    unsigned r = v.u + 0x7fff + ((v.u >> 16) & 1);   // RTNE
    return (short)(r >> 16);
}
__device__ __forceinline__ float bf2f(short h) {
    union { unsigned u; float f; } v; v.u = ((unsigned)(unsigned short)h) << 16;
    return v.f;
}

// ---------------- MFMA GEMM ----------------
// C[M,N] = A(M,K,lda) @ B^T where B is (N,K,ldb) row-major, fp32 in/out.
// PREC=1: plain bf16 (hi only). PREC=3: bf16x3 split (hi*hi + lo*hi + hi*lo) ~ fp32 accuracy.
// epilogue: v = acc (+C if beta) (+bias[n]) ; relu ; * mul[m,n]
// M must be a multiple of 128 (grid-implicit); N,K arbitrary (guarded).

template<int PREC, bool GUARD>
__device__ __forceinline__ void stage_tile(const float* __restrict__ src, int ld, int rowlim,
                                           int K, int k0, short (*Sh)[128][8], short (*Sl)[128][8],
                                           int tid)
{
    int quad = tid & 3;
    int r = tid >> 2;
    #pragma unroll
    for (int pass = 0; pass < 2; pass++) {
        int row = r + (pass << 6);
        bool rv = row < rowlim;
        const float* p = src + (size_t)row * ld + k0 + quad * 8;
        float f[8];
        if (rv && !GUARD) {
            float4 x = ((const float4*)p)[0];
            float4 y = ((const float4*)p)[1];
            f[0]=x.x; f[1]=x.y; f[2]=x.z; f[3]=x.w;
            f[4]=y.x; f[5]=y.y; f[6]=y.z; f[7]=y.w;
        } else {
            #pragma unroll
            for (int j = 0; j < 8; j++) {
                int k = k0 + quad * 8 + j;
                f[j] = (rv && k < K) ? p[j] : 0.f;
            }
        }
        bf8v hv;
        #pragma unroll
        for (int j = 0; j < 8; j++) hv[j] = f2bf(f[j]);
        *((bf8v*)Sh[quad][row]) = hv;
        if (PREC == 3) {
            bf8v lv;
            #pragma unroll
            for (int j = 0; j < 8; j++) lv[j] = f2bf(f[j] - bf2f(hv[j]));
            *((bf8v*)Sl[quad][row]) = lv;
        }
    }
}

template<int PREC>
__device__ __forceinline__ void compute_step(f4v (*acc)[4],
        short (*Ah)[128][8], short (*Al)[128][8],
        short (*Bh)[128][8], short (*Bl)[128][8], int tid)
{
    int lane = tid & 63, wid = tid >> 6;
    int wy = wid >> 1, wx = wid & 1;
    int quad = lane >> 4, l15 = lane & 15;
    bf8v ah[4], bh[4], al[4], bl[4];
    #pragma unroll
    for (int i = 0; i < 4; i++) {
        ah[i] = *((const bf8v*)Ah[quad][wy * 64 + i * 16 + l15]);
        bh[i] = *((const bf8v*)Bh[quad][wx * 64 + i * 16 + l15]);
        if (PREC == 3) {
            al[i] = *((const bf8v*)Al[quad][wy * 64 + i * 16 + l15]);
            bl[i] = *((const bf8v*)Bl[quad][wx * 64 + i * 16 + l15]);
        }
    }
    #pragma unroll
    for (int i = 0; i < 4; i++)
        #pragma unroll
        for (int j = 0; j < 4; j++) {
            acc[i][j] = __builtin_amdgcn_mfma_f32_16x16x32_bf16(ah[i], bh[j], acc[i][j], 0, 0, 0);
            if (PREC == 3) {
                acc[i][j] = __builtin_amdgcn_mfma_f32_16x16x32_bf16(al[i], bh[j], acc[i][j], 0, 0, 0);
                acc[i][j] = __builtin_amdgcn_mfma_f32_16x16x32_bf16(ah[i], bl[j], acc[i][j], 0, 0, 0);
            }
        }
}

template<int PREC>
__global__ __launch_bounds__(256, 2)
void mgemm_k(const float* __restrict__ A, int lda,
             const float* __restrict__ B, int ldb,
             float* __restrict__ C, int ldc,
             const float* __restrict__ bias,
             const float* __restrict__ mul, int ldmul,
             int N, int K, int beta, int relu)
{
    constexpr int LQ = (PREC == 3) ? 4 : 1;
    __shared__ __align__(16) short Ah[4][128][8];
    __shared__ __align__(16) short Bh[4][128][8];
    __shared__ __align__(16) short Al[LQ][128][8];
    __shared__ __align__(16) short Bl[LQ][128][8];
    int tid = threadIdx.x;
    int m0 = blockIdx.y * 128, n0 = blockIdx.x * 128;
    int rowlimB = N - n0; if (rowlimB > 128) rowlimB = 128;
    const float* Ab = A + (size_t)m0 * lda;
    const float* Bb = B + (size_t)n0 * ldb;
    f4v acc[4][4] = {};
    int K32 = K & ~31;
    for (int k0 = 0; k0 < K32; k0 += 32) {
        stage_tile<PREC, false>(Ab, lda, 128,     K, k0, Ah, Al, tid);
        stage_tile<PREC, false>(Bb, ldb, rowlimB, K, k0, Bh, Bl, tid);
        __syncthreads();
        compute_step<PREC>(acc, Ah, Al, Bh, Bl, tid);
        __syncthreads();
    }
    if (K32 < K) {
        stage_tile<PREC, true>(Ab, lda, 128,     K, K32, Ah, Al, tid);
        stage_tile<PREC, true>(Bb, ldb, rowlimB, K, K32, Bh, Bl, tid);
        __syncthreads();
        compute_step<PREC>(acc, Ah, Al, Bh, Bl, tid);
        __syncthreads();
    }
    // epilogue  (C/D layout: col = lane&15, row = quad*4 + reg  [m89-verified])
    int lane = tid & 63, wid = tid >> 6;
    int wy = wid >> 1, wx = wid & 1;
    int quad = lane >> 4, l15 = lane & 15;
    #pragma unroll
    for (int i = 0; i < 4; i++) {
        int mbase = m0 + wy * 64 + i * 16 + quad * 4;
        #pragma unroll
        for (int j = 0; j < 4; j++) {
            int n = n0 + wx * 64 + j * 16 + l15;
            if (n < N) {
                #pragma unroll
                for (int r = 0; r < 4; r++) {
                    int m = mbase + r;
                    float v = acc[i][j][r];
                    if (beta) v += C[(size_t)m * ldc + n];
                    if (bias) v += bias[n];
                    if (relu) v = fmaxf(v, 0.f);
                    if (mul)  v *= mul[(size_t)m * ldmul + n];
                    C[(size_t)m * ldc + n] = v;
                }
            }
        }
    }
}

static void mgemm(hipStream_t s, int prec, const float* A, int lda, const float* B, int ldb,
                  float* C, int ldc, const float* bias, const float* mul, int ldmul,
                  int M, int N, int K, int beta, int relu)
{
    dim3 grid((N + 127) / 128, M / 128);
    if (prec == 3)
        mgemm_k<3><<<grid, 256, 0, s>>>(A, lda, B, ldb, C, ldc, bias, mul, ldmul, N, K, beta, relu);
    else
        mgemm_k<1><<<grid, 256, 0, s>>>(A, lda, B, ldb, C, ldc, bias, mul, ldmul, N, K, beta, relu);
}

// ---------------- small kernels ----------------
__global__ void fill0_k(float* p, int n) {
    int i = blockIdx.x * 256 + threadIdx.x;
    if (i < n) p[i] = 0.f;
}

__global__ void embed_k(const int* __restrict__ q, const float* __restrict__ wemb, float* __restrict__ emb) {
    int i = blockIdx.x * 256 + threadIdx.x;
    if (i >= BATCH * QLEN_ * EMB) return;
    int e = i % EMB; int bt = i / EMB;
    emb[i] = wemb[(size_t)q[bt] * EMB + e];
}

__global__ void gru_point_k(const float* __restrict__ gi, int ldgi, const float* __restrict__ gh,
                            const int* __restrict__ qlen, float* __restrict__ h, int t) {
    int i = blockIdx.x * 256 + threadIdx.x;
    if (i >= BATCH * HID) return;
    int b = i / HID; int j = i % HID;
    float ir = gi[(size_t)b * ldgi + j];
    float iz = gi[(size_t)b * ldgi + HID + j];
    float in = gi[(size_t)b * ldgi + 2 * HID + j];
    float hr = gh[(size_t)b * 3 * HID + j];
    float hz = gh[(size_t)b * 3 * HID + HID + j];
    float hn = gh[(size_t)b * 3 * HID + 2 * HID + j];
    float r = 1.f / (1.f + expf(-(ir + hr)));
    float z = 1.f / (1.f + expf(-(iz + hz)));
    float n = tanhf(in + r * hn);
    float hold = h[i];
    float hnew = (1.f - z) * n + z * hold;
    h[i] = (t < qlen[b]) ? hnew : hold;
}

__global__ __launch_bounds__(256)
void attraw_k(const float* __restrict__ proj, const float* __restrict__ qproj,
              const float* __restrict__ attw, const float* __restrict__ attb,
              float* __restrict__ raw, int L) {
    int wave = blockIdx.x * 4 + (threadIdx.x >> 6);
    int lane = threadIdx.x & 63;
    if (wave >= BATCH * L) return;
    int b = wave / L;
    const float* p = proj + (size_t)wave * HID;
    const float* q = qproj + (size_t)b * HID;
    float s = 0.f;
    for (int hh = lane; hh < HID; hh += 64) s += p[hh] * q[hh] * attw[hh];
    #pragma unroll
    for (int o = 32; o; o >>= 1) s += __shfl_down(s, o, 64);
    if (lane == 0) raw[wave] = s + attb[0];
}

__global__ void softmax_k(float* raw, int L) {
    int b = blockIdx.x * blockDim.x + threadIdx.x;
    if (b >= BATCH) return;
    float* r = raw + (size_t)b * L;
    float mx = -1e30f;
    for (int l = 0; l < L; l++) mx = fmaxf(mx, r[l]);
    float sum = 0.f;
    for (int l = 0; l < L; l++) { float e = expf(r[l] - mx); r[l] = e; sum += e; }
    float inv = 1.f / sum;
    for (int l = 0; l < L; l++) r[l] *= inv;
}

__global__ void wsum_k(const float* __restrict__ src, const float* __restrict__ att,
                       float* __restrict__ out, int L, int F, int out_ld, int out_off) {
    int i = blockIdx.x * 256 + threadIdx.x;
    if (i >= BATCH * F) return;
    int b = i / F, f = i % F;
    float s = 0.f;
    for (int l = 0; l < L; l++) s += src[((size_t)b * L + l) * F + f] * att[b * L + l];
    out[(size_t)b * out_ld + out_off + f] = s;
}

// jax.lax.top_k: descending, ties -> lowest index
__global__ void topk_k(const float* __restrict__ att, int* __restrict__ idx) {
    int b = blockIdx.x * blockDim.x + threadIdx.x;
    if (b >= BATCH) return;
    float v[KOBJ]; bool taken[KOBJ];
    for (int l = 0; l < KOBJ; l++) { v[l] = att[(size_t)b * KOBJ + l]; taken[l] = false; }
    for (int s = 0; s < NS; s++) {
        float best = -1e30f; int bi = 0;
        for (int l = 0; l < KOBJ; l++)
            if (!taken[l] && v[l] > best) { best = v[l]; bi = l; }
        taken[bi] = true;
        idx[b * NS + s] = bi;
    }
}

__global__ void gather_k(const float* __restrict__ img, const int* __restrict__ idx, float* __restrict__ out) {
    int i = blockIdx.x * 256 + threadIdx.x;
    if (i >= BATCH * NS * FEAT) return;
    int f = i % FEAT; int bs = i / FEAT; int b = bs / NS; int s = bs % NS;
    out[i] = img[((size_t)b * KOBJ + idx[b * NS + s]) * FEAT + f];
}

__global__ void kw_k(const float* __restrict__ image, const int* __restrict__ tidx,
                     const float* __restrict__ mu1, const float* __restrict__ sig1,
                     const float* __restrict__ mu2, const float* __restrict__ sig2,
                     float* __restrict__ kw1, float* __restrict__ kw2) {
    int i = blockIdx.x * blockDim.x + threadIdx.x;
    if (i >= BATCH * NS * NS) return;
    int m = i % NS; int bn = i / NS; int b = bn / NS; int n = bn % NS;
    const float* bbn = image + ((size_t)b * KOBJ + tidx[b * NS + n]) * FEAT + (FEAT - 4);
    const float* bbm = image + ((size_t)b * KOBJ + tidx[b * NS + m]) * FEAT + (FEAT - 4);
    float cnx = bbn[0] + 0.5f * (bbn[2] - bbn[0]);
    float cny = bbn[1] + 0.5f * (bbn[3] - bbn[1]);
    float cmx = bbm[0] + 0.5f * (bbm[2] - bbm[0]);
    float cmy = bbm[1] + 0.5f * (bbm[3] - bbm[1]);
    float d0 = cnx - cmx, d1 = cny - cmy;
    float rho = sqrtf(d0 * d0 + d1 * d1);
    float theta = atan2f(d0, d1);
    #pragma unroll
    for (int k = 0; k < NK; k++) {
        float a1 = (rho   - mu1[k * 2 + 0]) / (1e-14f + sig1[k * 2 + 0]);
        float b1 = (theta - mu1[k * 2 + 1]) / (1e-14f + sig1[k * 2 + 1]);
        kw1[(size_t)i * NK + k] = expf(-0.5f * (a1 * a1 + b1 * b1));
        float a2 = (rho   - mu2[k * 2 + 0]) / (1e-14f + sig2[k * 2 + 0]);
        float b2 = (theta - mu2[k * 2 + 1]) / (1e-14f + sig2[k * 2 + 1]);
        kw2[(size_t)i * NK + k] = expf(-0.5f * (a2 * a2 + b2 * b2));
    }
}

__global__ void mix_k(const float* __restrict__ Y, const float* __restrict__ kw,
                      const float* __restrict__ bias, float* __restrict__ out,
                      int KO, int CT) {
    int i = blockIdx.x * blockDim.x + threadIdx.x;
    if (i >= BATCH * NS * CT) return;
    int c = i % CT; int bn = i / CT; int b = bn / NS;
    int k = c / KO;
    float s = bias[c];
    const float* kwp = kw + ((size_t)bn * NS) * NK + k;
    const float* Yp  = Y + ((size_t)b * NS) * CT + c;
    #pragma unroll
    for (int m = 0; m < NS; m++) s += kwp[m * NK] * Yp[(size_t)m * CT];
    out[i] = fmaxf(s, 0.f);
}

// tiled transpose per k-slice: dst[o][f] = src[f][o]; src slice S x O, dst slice O x S
__global__ void pack_k(const float* __restrict__ src, float* __restrict__ dst, int S, int O) {
    __shared__ float t[32][33];
    int k = blockIdx.z;
    const float* s = src + (size_t)k * S * O;
    float* d = dst + (size_t)k * O * S;
    int f0 = blockIdx.y * 32, o0 = blockIdx.x * 32;
    for (int i = threadIdx.y; i < 32; i += 8) {
        int f = f0 + i, o = o0 + threadIdx.x;
        if (f < S && o < O) t[i][threadIdx.x] = s[(size_t)f * O + o];
    }
    __syncthreads();
    for (int i = threadIdx.y; i < 32; i += 8) {
        int o = o0 + i, f = f0 + threadIdx.x;
        if (o < O && f < S) d[(size_t)o * S + f] = t[threadIdx.x][i];
    }
}

// ---------------- launch ----------------
extern "C" void kernel_launch(void* const* d_in, const int* in_sizes, int n_in,
                              void* d_out, int out_size, void* d_ws, size_t ws_size,
                              hipStream_t stream)
{
    const int*   question  = (const int*)d_in[0];
    const float* image     = (const float*)d_in[1];
    const int*   qlen      = (const int*)d_in[3];
    const float* wembed    = (const float*)d_in[4];
    const float* gru_wih   = (const float*)d_in[5];
    const float* gru_whh   = (const float*)d_in[6];
    const float* gru_bih   = (const float*)d_in[7];
    const float* gru_bhh   = (const float*)d_in[8];
    const float* ia_img_w  = (const float*)d_in[9];
    const float* ia_img_b  = (const float*)d_in[10];
    const float* ia_txt_w  = (const float*)d_in[11];
    const float* ia_txt_b  = (const float*)d_in[12];
    const float* ia_att_w  = (const float*)d_in[13];
    const float* ia_att_b  = (const float*)d_in[14];
    const float* ga_img_w  = (const float*)d_in[15];
    const float* ga_img_b  = (const float*)d_in[16];
    const float* ga_txt_w  = (const float*)d_in[17];
    const float* ga_txt_b  = (const float*)d_in[18];
    const float* ga_att_w  = (const float*)d_in[19];
    const float* ga_att_b  = (const float*)d_in[20];
    const float* gc1_mu    = (const float*)d_in[21];
    const float* gc1_sigma = (const float*)d_in[22];
    const float* gc1_w     = (const float*)d_in[23];
    const float* gc1_b     = (const float*)d_in[24];
    const float* gc2_mu    = (const float*)d_in[25];
    const float* gc2_sigma = (const float*)d_in[26];
    const float* gc2_w     = (const float*)d_in[27];
    const float* gc2_b     = (const float*)d_in[28];
    const float* out1_w    = (const float*)d_in[29];
    const float* out1_b    = (const float*)d_in[30];
    const float* out2_w    = (const float*)d_in[31];
    const float* out2_b    = (const float*)d_in[32];
    const float* iout1_w   = (const float*)d_in[33];
    const float* iout1_b   = (const float*)d_in[34];
    const float* iout2_w   = (const float*)d_in[35];
    const float* iout2_b   = (const float*)d_in[36];
    float* out = (float*)d_out;

    float* ws = (float*)d_ws;
    size_t off = 0;
    auto alloc = [&](size_t n) { size_t o = off; off += (n + 63) & ~(size_t)63; return ws + o; };

    // scratch region R1 (phase-reused)
    float* R1 = alloc(12871680);
    // persistent
    float* qenc   = alloc((size_t)BATCH * HID);
    float* icomb  = alloc((size_t)BATCH * HID);
    float* gcomb  = alloc((size_t)BATCH * HID);
    float* att_ia = alloc((size_t)BATCH * KOBJ);
    float* att_ga = alloc((size_t)BATCH * NS);
    int*   tidx   = (int*)alloc((size_t)BATCH * NS);
    float* timg   = alloc((size_t)BATCH * NS * FEAT);
    float* kw1    = alloc((size_t)BATCH * NS * NS * NK);
    float* kw2    = alloc((size_t)BATCH * NS * NS * NK);
    float* h1     = alloc((size_t)BATCH * NS * 2 * HID);
    float* h2     = alloc((size_t)BATCH * NS * HID);
    float* gc1t   = alloc((size_t)2 * HID * FEAT);   // (2048 x 2052)
    float* gc2t   = alloc((size_t)HID * 2 * HID);    // (1024 x 2048)

    // ===== Phase A: GRU encoder =====
    float* emb    = R1;                      // 3584 x 300
    float* gi_all = R1 + 1075200;            // 3584 x 3072
    float* gh     = R1 + 1075200 + 11010048; // 256 x 3072
    fill0_k<<<(BATCH * HID + 255) / 256, 256, 0, stream>>>(qenc, BATCH * HID);
    embed_k<<<(BATCH * QLEN_ * EMB + 255) / 256, 256, 0, stream>>>(question, wembed, emb);
    mgemm(stream, 3, emb, EMB, gru_wih, EMB, gi_all, 3 * HID,
          gru_bih, nullptr, 0, BATCH * QLEN_, 3 * HID, EMB, 0, 0);
    for (int t = 0; t < QLEN_; t++) {
        mgemm(stream, 3, qenc, HID, gru_whh, HID, gh, 3 * HID,
              gru_bhh, nullptr, 0, BATCH, 3 * HID, HID, 0, 0);
        gru_point_k<<<(BATCH * HID + 255) / 256, 256, 0, stream>>>(
            gi_all + (size_t)t * 3 * HID, QLEN_ * 3 * HID, gh, qlen, qenc, t);
    }

    // ===== Phase B: image attention (scoring path = PREC3) =====
    float* improj = R1;                  // 9216 x 1024
    float* qproj  = R1 + 9437184;        // 256 x 1024
    float* imatt  = R1 + 9437184 + 262144; // 256 x 2052
    mgemm(stream, 3, image, FEAT, ia_img_w, FEAT, improj, HID,
          ia_img_b, nullptr, 0, BATCH * KOBJ, HID, FEAT, 0, 1);
    mgemm(stream, 3, qenc, HID, ia_txt_w, HID, qproj, HID,
          ia_txt_b, nullptr, 0, BATCH, HID, HID, 0, 1);
    attraw_k<<<(BATCH * KOBJ) / 4, 256, 0, stream>>>(improj, qproj, ia_att_w, ia_att_b, att_ia, KOBJ);
    softmax_k<<<1, 256, 0, stream>>>(att_ia, KOBJ);
    wsum_k<<<(BATCH * FEAT + 255) / 256, 256, 0, stream>>>(image, att_ia, imatt, KOBJ, FEAT, FEAT, 0);
    mgemm(stream, 1, imatt, FEAT, ia_img_w, FEAT, icomb, HID,
          ia_img_b, qproj, HID, BATCH, HID, FEAT, 0, 1);

    // ===== Phase C: top-k + graph convs =====
    topk_k<<<1, 256, 0, stream>>>(att_ia, tidx);
    gather_k<<<(BATCH * NS * FEAT + 255) / 256, 256, 0, stream>>>(image, tidx, timg);
    kw_k<<<(BATCH * NS * NS + 255) / 256, 256, 0, stream>>>(image, tidx, gc1_mu, gc1_sigma, gc2_mu, gc2_sigma, kw1, kw2);
    float* Y1 = R1;            // 2560 x 2048
    float* Y2 = R1 + 5242880;  // 2560 x 1024
    pack_k<<<dim3(8, 65, NK), dim3(32, 8), 0, stream>>>(gc1_w, gc1t, FEAT, 256);
    mgemm(stream, 1, timg, FEAT, gc1t, FEAT, Y1, 2 * HID,
          nullptr, nullptr, 0, BATCH * NS, 2 * HID, FEAT, 0, 0);
    mix_k<<<(BATCH * NS * 2 * HID + 255) / 256, 256, 0, stream>>>(Y1, kw1, gc1_b, h1, 256, 2 * HID);
    pack_k<<<dim3(4, 64, NK), dim3(32, 8), 0, stream>>>(gc2_w, gc2t, 2 * HID, 128);
    mgemm(stream, 1, h1, 2 * HID, gc2t, 2 * HID, Y2, HID,
          nullptr, nullptr, 0, BATCH * NS, HID, 2 * HID, 0, 0);
    mix_k<<<(BATCH * NS * HID + 255) / 256, 256, 0, stream>>>(Y2, kw2, gc2_b, h2, 128, HID);

    // ===== Phase D: graph attention ([timg | h2] never materialized) =====
    float* gproj  = R1;                    // 2560 x 1024
    float* qproj2 = R1 + 2621440;          // 256 x 1024
    float* gatt   = R1 + 2621440 + 262144; // 256 x 3076
    mgemm(stream, 1, timg, FEAT, ga_img_w, FEAT + HID, gproj, HID,
          nullptr, nullptr, 0, BATCH * NS, HID, FEAT, 0, 0);
    mgemm(stream, 1, h2, HID, ga_img_w + FEAT, FEAT + HID, gproj, HID,
          ga_img_b, nullptr, 0, BATCH * NS, HID, HID, 1, 1);
    mgemm(stream, 1, qenc, HID, ga_txt_w, HID, qproj2, HID,
          ga_txt_b, nullptr, 0, BATCH, HID, HID, 0, 1);
    attraw_k<<<(BATCH * NS) / 4, 256, 0, stream>>>(gproj, qproj2, ga_att_w, ga_att_b, att_ga, NS);
    softmax_k<<<1, 256, 0, stream>>>(att_ga, NS);
    wsum_k<<<(BATCH * FEAT + 255) / 256, 256, 0, stream>>>(timg, att_ga, gatt, NS, FEAT, FEAT + HID, 0);
    wsum_k<<<(BATCH * HID + 255) / 256, 256, 0, stream>>>(h2, att_ga, gatt, NS, HID, FEAT + HID, FEAT);
    mgemm(stream, 1, gatt, FEAT + HID, ga_img_w, FEAT + HID, gcomb, HID,
          ga_img_b, qproj2, HID, BATCH, HID, FEAT + HID, 0, 1);

    // ===== Phase E: output MLPs =====
    float* hid1 = R1;
    float* hid2 = R1 + 768000;
    mgemm(stream, 1, gcomb, HID, out1_w, HID, hid1, OUTN,
          out1_b, nullptr, 0, BATCH, OUTN, HID, 0, 1);
    mgemm(stream, 1, icomb, HID, iout1_w, HID, hid2, OUTN,
          iout1_b, nullptr, 0, BATCH, OUTN, HID, 0, 1);
    mgemm(stream, 1, hid1, OUTN, out2_w, OUTN, out, OUTN,
          out2_b, nullptr, 0, BATCH, OUTN, OUTN, 0, 0);
    mgemm(stream, 1, hid2, OUTN, iout2_w, OUTN, out, OUTN,
          iout2_b, nullptr, 0, BATCH, OUTN, OUTN, 1, 0);
}

// Round 3
// 2140.752 us; speedup vs baseline: 4.9918x; 1.6616x over previous
//
#include <hip/hip_runtime.h>
#include <cmath>

#define VOCAB 20000
#define EMB 300
#define FEAT 2052
#define HID 1024
#define OUTN 3000
#define NK 8
#define NS 10
#define KOBJ 36
#define BATCH 256
#define QLEN_ 14

typedef __attribute__((ext_vector_type(8))) short bf8v;
typedef __attribute__((ext_vector_type(4))) float f4v;

__device__ __forceinline__ short f2bf(float f) {
    union { float f; unsigned u; } v; v.f = f;
    unsigned r = v.u + 0x7fff + ((v.u >> 16) & 1);   // RTNE
    return (short)(r >> 16);
}
__device__ __forceinline__ float bf2f(short h) {
    union { unsigned u; float f; } v; v.u = ((unsigned)(unsigned short)h) << 16;
    return v.f;
}

// async global->LDS, 16B per lane, dest = ldsbase + lane*16 (wave-uniform base)
__device__ __forceinline__ void gload16(const short* g, short* l) {
    typedef __attribute__((address_space(1))) void gv;
    typedef __attribute__((address_space(3))) void lv;
    __builtin_amdgcn_global_load_lds((gv*)g, (lv*)l, 16, 0, 0);
}

// ---------------- MFMA GEMM (bf16-in, m97-style staging) ----------------
// C[M,N] = A(M,K) @ B^T, A/B pre-converted bf16 (hi[,lo]) with K%32==0, rows padded.
// PREC=3: bf16x3 split (hi*hi + lo*hi + hi*lo). MI=4 -> BM=128, MI=2 -> BM=64. BN=128.
// epilogue: v = acc (+C if beta) (+bias) ; relu ; *mul ; write fp32 C and/or bf16 Cb.
template<int PREC, int MI>
__global__ __launch_bounds__(256)
void mgemm_k(const short* __restrict__ Ah_g, const short* __restrict__ Al_g, int lda,
             const short* __restrict__ Bh_g, const short* __restrict__ Bl_g, int ldb,
             float* __restrict__ Cf, int ldc,
             short* __restrict__ Cb, int ldcb,
             const float* __restrict__ bias,
             const float* __restrict__ mul, int ldmul,
             int Nvalid, int K, int beta, int relu)
{
    constexpr int BM  = MI * 32;
    constexpr int ASZ = BM * 32;          // shorts
    constexpr int BSZ = 128 * 32;
    __shared__ short SA[ASZ];
    __shared__ short SB[BSZ];
    __shared__ short SAl[PREC == 3 ? ASZ : 16];
    __shared__ short SBl[PREC == 3 ? BSZ : 16];

    // XCD-aware swizzle: give each XCD (flat%8) a contiguous rank range so the
    // N-blocks sharing an A-strip land on the same XCD's L2.
    int gx = gridDim.x;
    int flat = blockIdx.y * gx + blockIdx.x;
    int total = gx * gridDim.y;
    int bx, by;
    if ((total & 7) == 0) {
        int r = (flat & 7) * (total >> 3) + (flat >> 3);
        by = r / gx; bx = r - by * gx;
    } else { bx = blockIdx.x; by = blockIdx.y; }

    int tid = threadIdx.x;
    int lane = tid & 63, wid = tid >> 6;
    int m0 = by * BM, n0 = bx * 128;
    const short* Ab  = Ah_g + (size_t)m0 * lda;
    const short* Bb  = Bh_g + (size_t)n0 * ldb;
    const short* Abl = (PREC == 3) ? Al_g + (size_t)m0 * lda : nullptr;
    const short* Bbl = (PREC == 3) ? Bl_g + (size_t)n0 * ldb : nullptr;

    constexpr int AISS = BM / 16;                         // 16-row issues per A tile
    constexpr int NISS = (PREC == 3) ? 2 * (AISS + 8) : (AISS + 8);
    int rr = lane & 15;            // row within 16-row group
    int cc = (lane >> 4) * 8;      // k-offset (8 bf16 = 16B)

    f4v acc[MI][4] = {};
    for (int k0 = 0; k0 < K; k0 += 32) {
        #pragma unroll
        for (int t = wid; t < NISS; t += 4) {
            int u = t;
            const short* g; short* l;
            if (u < AISS)              {                   g = Ab  + (size_t)(u*16+rr)*lda + k0 + cc; l = SA  + u*512; }
            else if (u < AISS + 8)     { u -= AISS;        g = Bb  + (size_t)(u*16+rr)*ldb + k0 + cc; l = SB  + u*512; }
            else if (u < 2*AISS + 8)   { u -= AISS + 8;    g = Abl + (size_t)(u*16+rr)*lda + k0 + cc; l = SAl + u*512; }
            else                       { u -= 2*AISS + 8;  g = Bbl + (size_t)(u*16+rr)*ldb + k0 + cc; l = SBl + u*512; }
            gload16(g, l);
        }
        __syncthreads();
        {
            int wy = wid >> 1, wx = wid & 1;
            int quad = lane >> 4, l15 = lane & 15;
            const bf8v* A8 = (const bf8v*)SA;
            const bf8v* B8 = (const bf8v*)SB;
            bf8v ah[MI], bh[4];
            #pragma unroll
            for (int i = 0; i < MI; i++) ah[i] = A8[(wy*MI + i)*64 + quad*16 + l15];
            #pragma unroll
            for (int j = 0; j < 4; j++)  bh[j] = B8[(wx*4 + j)*64 + quad*16 + l15];
            if (PREC == 3) {
                const bf8v* A8l = (const bf8v*)SAl;
                const bf8v* B8l = (const bf8v*)SBl;
                bf8v al[MI], bl[4];
                #pragma unroll
                for (int i = 0; i < MI; i++) al[i] = A8l[(wy*MI + i)*64 + quad*16 + l15];
                #pragma unroll
                for (int j = 0; j < 4; j++)  bl[j] = B8l[(wx*4 + j)*64 + quad*16 + l15];
                #pragma unroll
                for (int i = 0; i < MI; i++)
                    #pragma unroll
                    for (int j = 0; j < 4; j++) {
                        acc[i][j] = __builtin_amdgcn_mfma_f32_16x16x32_bf16(ah[i], bh[j], acc[i][j], 0, 0, 0);
                        acc[i][j] = __builtin_amdgcn_mfma_f32_16x16x32_bf16(al[i], bh[j], acc[i][j], 0, 0, 0);
                        acc[i][j] = __builtin_amdgcn_mfma_f32_16x16x32_bf16(ah[i], bl[j], acc[i][j], 0, 0, 0);
                    }
            } else {
                #pragma unroll
                for (int i = 0; i < MI; i++)
                    #pragma unroll
                    for (int j = 0; j < 4; j++)
                        acc[i][j] = __builtin_amdgcn_mfma_f32_16x16x32_bf16(ah[i], bh[j], acc[i][j], 0, 0, 0);
            }
        }
        __syncthreads();
    }
    // epilogue (C/D: col = lane&15, row = quad*4 + reg)
    int wy = wid >> 1, wx = wid & 1;
    int quad = lane >> 4, l15 = lane & 15;
    #pragma unroll
    for (int i = 0; i < MI; i++) {
        int mb = m0 + wy * (MI * 16) + i * 16 + quad * 4;
        #pragma unroll
        for (int j = 0; j < 4; j++) {
            int n = n0 + wx * 64 + j * 16 + l15;
            bool nin = n < Nvalid;
            #pragma unroll
            for (int r = 0; r < 4; r++) {
                int m = mb + r;
                float v = acc[i][j][r];
                if (nin) {
                    if (beta) v += Cf[(size_t)m * ldc + n];
                    if (bias) v += bias[n];
                    if (relu) v = fmaxf(v, 0.f);
                    if (mul)  v *= mul[(size_t)m * ldmul + n];
                    if (Cf) Cf[(size_t)m * ldc + n] = v;
                    if (Cb) Cb[(size_t)m * ldcb + n] = f2bf(v);
                } else if (Cb && n < ldcb) {
                    Cb[(size_t)m * ldcb + n] = 0;   // zero-fill K-pad cols of bf16 outputs
                }
            }
        }
    }
}

static void mg(hipStream_t s, int prec, int mi,
               const short* Ah, const short* Al, int lda,
               const short* Bh, const short* Bl, int ldb,
               float* Cf, int ldc, short* Cb, int ldcb,
               const float* bias, const float* mul, int ldmul,
               int M, int N, int K, int beta, int relu)
{
    dim3 grid((N + 127) / 128, M / (mi * 32));
    if (prec == 3) {
        if (mi == 4) mgemm_k<3,4><<<grid,256,0,s>>>(Ah,Al,lda,Bh,Bl,ldb,Cf,ldc,Cb,ldcb,bias,mul,ldmul,N,K,beta,relu);
        else         mgemm_k<3,2><<<grid,256,0,s>>>(Ah,Al,lda,Bh,Bl,ldb,Cf,ldc,Cb,ldcb,bias,mul,ldmul,N,K,beta,relu);
    } else {
        if (mi == 4) mgemm_k<1,4><<<grid,256,0,s>>>(Ah,Al,lda,Bh,Bl,ldb,Cf,ldc,Cb,ldcb,bias,mul,ldmul,N,K,beta,relu);
        else         mgemm_k<1,2><<<grid,256,0,s>>>(Ah,Al,lda,Bh,Bl,ldb,Cf,ldc,Cb,ldcb,bias,mul,ldmul,N,K,beta,relu);
    }
}

// ---------------- conversion / small kernels ----------------
__global__ void fill0_k(float* p, int n) {
    int i = blockIdx.x * 256 + threadIdx.x;
    if (i < n) p[i] = 0.f;
}

// fp32 (srows,scols,sld) -> bf16 hi[,lo] (.., dld) zero-padded
__global__ void cvt_k(const float* __restrict__ src, int sld, int srows, int scols,
                      short* __restrict__ hi, short* __restrict__ lo, int dld, int n) {
    int i = blockIdx.x * 256 + threadIdx.x;
    if (i >= n) return;
    int r = i / dld, c = i - r * dld;
    float v = (r < srows && c < scols) ? src[(size_t)r * sld + c] : 0.f;
    short h = f2bf(v);
    hi[i] = h;
    if (lo) lo[i] = f2bf(v - bf2f(h));
}

__global__ void embed_k(const int* __restrict__ q, const float* __restrict__ wemb,
                        short* __restrict__ hi, short* __restrict__ lo) {
    int i = blockIdx.x * 256 + threadIdx.x;
    if (i >= BATCH * QLEN_ * 320) return;
    int c = i % 320; int bt = i / 320;
    float v = (c < EMB) ? wemb[(size_t)q[bt] * EMB + c] : 0.f;
    short h = f2bf(v);
    hi[i] = h;
    lo[i] = f2bf(v - bf2f(h));
}

__global__ void gru_point_k(const float* __restrict__ gi, int ldgi, const float* __restrict__ gh,
                            const int* __restrict__ qlen, float* __restrict__ h,
                            short* __restrict__ qh, short* __restrict__ ql, int t) {
    int i = blockIdx.x * 256 + threadIdx.x;
    if (i >= BATCH * HID) return;
    int b = i / HID; int j = i % HID;
    float ir = gi[(size_t)b * ldgi + j];
    float iz = gi[(size_t)b * ldgi + HID + j];
    float in = gi[(size_t)b * ldgi + 2 * HID + j];
    float hr = gh[(size_t)b * 3 * HID + j];
    float hz = gh[(size_t)b * 3 * HID + HID + j];
    float hn = gh[(size_t)b * 3 * HID + 2 * HID + j];
    float r = 1.f / (1.f + expf(-(ir + hr)));
    float z = 1.f / (1.f + expf(-(iz + hz)));
    float n = tanhf(in + r * hn);
    float hold = h[i];
    float val = (t < qlen[b]) ? ((1.f - z) * n + z * hold) : hold;
    h[i] = val;
    short hh = f2bf(val);
    qh[i] = hh;
    ql[i] = f2bf(val - bf2f(hh));
}

__global__ __launch_bounds__(256)
void attraw_k(const float* __restrict__ proj, const float* __restrict__ qproj,
              const float* __restrict__ attw, const float* __restrict__ attb,
              float* __restrict__ raw, int L) {
    int wave = blockIdx.x * 4 + (threadIdx.x >> 6);
    int lane = threadIdx.x & 63;
    if (wave >= BATCH * L) return;
    int b = wave / L;
    const float* p = proj + (size_t)wave * HID;
    const float* q = qproj + (size_t)b * HID;
    float s = 0.f;
    for (int hh = lane; hh < HID; hh += 64) s += p[hh] * q[hh] * attw[hh];
    #pragma unroll
    for (int o = 32; o; o >>= 1) s += __shfl_down(s, o, 64);
    if (lane == 0) raw[wave] = s + attb[0];
}

__global__ void softmax_k(float* raw, int L) {
    int b = blockIdx.x * blockDim.x + threadIdx.x;
    if (b >= BATCH) return;
    float* r = raw + (size_t)b * L;
    float mx = -1e30f;
    for (int l = 0; l < L; l++) mx = fmaxf(mx, r[l]);
    float sum = 0.f;
    for (int l = 0; l < L; l++) { float e = expf(r[l] - mx); r[l] = e; sum += e; }
    float inv = 1.f / sum;
    for (int l = 0; l < L; l++) r[l] *= inv;
}

// bf16-out weighted sum with K-pad: out[b, c<dld] = sum_l src[(b*L+l)*sF + c] * att[b*L+l]
__global__ void wsumb_k(const float* __restrict__ src, int sF, const float* __restrict__ att,
                        int L, short* __restrict__ outh, int dld, int n) {
    int i = blockIdx.x * 256 + threadIdx.x;
    if (i >= n) return;
    int c = i % dld; int b = i / dld;
    float s = 0.f;
    if (c < sF)
        for (int l = 0; l < L; l++) s += src[((size_t)b * L + l) * sF + c] * att[b * L + l];
    outh[i] = f2bf(s);
}

// jax.lax.top_k: descending, ties -> lowest index
__global__ void topk_k(const float* __restrict__ att, int* __restrict__ idx) {
    int b = blockIdx.x * blockDim.x + threadIdx.x;
    if (b >= BATCH) return;
    float v[KOBJ]; bool taken[KOBJ];
    for (int l = 0; l < KOBJ; l++) { v[l] = att[(size_t)b * KOBJ + l]; taken[l] = false; }
    for (int s = 0; s < NS; s++) {
        float best = -1e30f; int bi = 0;
        for (int l = 0; l < KOBJ; l++)
            if (!taken[l] && v[l] > best) { best = v[l]; bi = l; }
        taken[bi] = true;
        idx[b * NS + s] = bi;
    }
}

// gather top-k rows: fp32 (ld 2052) + bf16 hi (ld 2080, zero pad)
__global__ void gather_k(const float* __restrict__ img, const int* __restrict__ idx,
                         float* __restrict__ outf, short* __restrict__ outh) {
    int i = blockIdx.x * 256 + threadIdx.x;
    if (i >= BATCH * NS * 2080) return;
    int c = i % 2080; int bs = i / 2080; int b = bs / NS; int s = bs % NS;
    float v = 0.f;
    if (c < FEAT) {
        v = img[((size_t)b * KOBJ + idx[b * NS + s]) * FEAT + c];
        outf[(size_t)bs * FEAT + c] = v;
    }
    outh[i] = f2bf(v);
}

__global__ void kw_k(const float* __restrict__ image, const int* __restrict__ tidx,
                     const float* __restrict__ mu1, const float* __restrict__ sig1,
                     const float* __restrict__ mu2, const float* __restrict__ sig2,
                     float* __restrict__ kw1, float* __restrict__ kw2) {
    int i = blockIdx.x * blockDim.x + threadIdx.x;
    if (i >= BATCH * NS * NS) return;
    int m = i % NS; int bn = i / NS; int b = bn / NS; int n = bn % NS;
    const float* bbn = image + ((size_t)b * KOBJ + tidx[b * NS + n]) * FEAT + (FEAT - 4);
    const float* bbm = image + ((size_t)b * KOBJ + tidx[b * NS + m]) * FEAT + (FEAT - 4);
    float cnx = bbn[0] + 0.5f * (bbn[2] - bbn[0]);
    float cny = bbn[1] + 0.5f * (bbn[3] - bbn[1]);
    float cmx = bbm[0] + 0.5f * (bbm[2] - bbm[0]);
    float cmy = bbm[1] + 0.5f * (bbm[3] - bbm[1]);
    float d0 = cnx - cmx, d1 = cny - cmy;
    float rho = sqrtf(d0 * d0 + d1 * d1);
    float theta = atan2f(d0, d1);
    #pragma unroll
    for (int k = 0; k < NK; k++) {
        float a1 = (rho   - mu1[k * 2 + 0]) / (1e-14f + sig1[k * 2 + 0]);
        float b1 = (theta - mu1[k * 2 + 1]) / (1e-14f + sig1[k * 2 + 1]);
        kw1[(size_t)i * NK + k] = expf(-0.5f * (a1 * a1 + b1 * b1));
        float a2 = (rho   - mu2[k * 2 + 0]) / (1e-14f + sig2[k * 2 + 0]);
        float b2 = (theta - mu2[k * 2 + 1]) / (1e-14f + sig2[k * 2 + 1]);
        kw2[(size_t)i * NK + k] = expf(-0.5f * (a2 * a2 + b2 * b2));
    }
}

// out[(b,n),c] = relu(bias[c] + sum_m kw[bn,m,k] * Y[(b,m),c]), k=c/KO; bf16 (+opt fp32)
__global__ void mix_k(const float* __restrict__ Y, const float* __restrict__ kw,
                      const float* __restrict__ bias, short* __restrict__ outh,
                      float* __restrict__ outf, int KO, int CT) {
    int i = blockIdx.x * blockDim.x + threadIdx.x;
    if (i >= BATCH * NS * CT) return;
    int c = i % CT; int bn = i / CT; int b = bn / NS;
    int k = c / KO;
    float s = bias[c];
    const float* kwp = kw + ((size_t)bn * NS) * NK + k;
    const float* Yp  = Y + ((size_t)b * NS) * CT + c;
    #pragma unroll
    for (int m = 0; m < NS; m++) s += kwp[m * NK] * Yp[(size_t)m * CT];
    s = fmaxf(s, 0.f);
    outh[i] = f2bf(s);
    if (outf) outf[i] = s;
}

// transpose+convert per k-slice: dst[k*O+o][f<dld] = src[k][f][o] (zero-pad f>=S)
__global__ void packcvt_k(const float* __restrict__ src, short* __restrict__ dst,
                          int S, int O, int dld) {
    __shared__ float t[32][33];
    int k = blockIdx.z;
    const float* s = src + (size_t)k * S * O;
    short* d = dst + (size_t)k * O * dld;
    int f0 = blockIdx.y * 32, o0 = blockIdx.x * 32;
    for (int i = threadIdx.y; i < 32; i += 8) {
        int f = f0 + i, o = o0 + threadIdx.x;
        t[i][threadIdx.x] = (f < S && o < O) ? s[(size_t)f * O + o] : 0.f;
    }
    __syncthreads();
    for (int i = threadIdx.y; i < 32; i += 8) {
        int o = o0 + i, f = f0 + threadIdx.x;
        if (o < O && f < dld) d[(size_t)o * dld + f] = f2bf(t[threadIdx.x][i]);
    }
}

// ---------------- launch ----------------
extern "C" void kernel_launch(void* const* d_in, const int* in_sizes, int n_in,
                              void* d_out, int out_size, void* d_ws, size_t ws_size,
                              hipStream_t stream)
{
    const int*   question  = (const int*)d_in[0];
    const float* image     = (const float*)d_in[1];
    const int*   qlen      = (const int*)d_in[3];
    const float* wembed    = (const float*)d_in[4];
    const float* gru_wih   = (const float*)d_in[5];
    const float* gru_whh   = (const float*)d_in[6];
    const float* gru_bih   = (const float*)d_in[7];
    const float* gru_bhh   = (const float*)d_in[8];
    const float* ia_img_w  = (const float*)d_in[9];
    const float* ia_img_b  = (const float*)d_in[10];
    const float* ia_txt_w  = (const float*)d_in[11];
    const float* ia_txt_b  = (const float*)d_in[12];
    const float* ia_att_w  = (const float*)d_in[13];
    const float* ia_att_b  = (const float*)d_in[14];
    const float* ga_img_w  = (const float*)d_in[15];
    const float* ga_img_b  = (const float*)d_in[16];
    const float* ga_txt_w  = (const float*)d_in[17];
    const float* ga_txt_b  = (const float*)d_in[18];
    const float* ga_att_w  = (const float*)d_in[19];
    const float* ga_att_b  = (const float*)d_in[20];
    const float* gc1_mu    = (const float*)d_in[21];
    const float* gc1_sigma = (const float*)d_in[22];
    const float* gc1_w     = (const float*)d_in[23];
    const float* gc1_b     = (const float*)d_in[24];
    const float* gc2_mu    = (const float*)d_in[25];
    const float* gc2_sigma = (const float*)d_in[26];
    const float* gc2_w     = (const float*)d_in[27];
    const float* gc2_b     = (const float*)d_in[28];
    const float* out1_w    = (const float*)d_in[29];
    const float* out1_b    = (const float*)d_in[30];
    const float* out2_w    = (const float*)d_in[31];
    const float* out2_b    = (const float*)d_in[32];
    const float* iout1_w   = (const float*)d_in[33];
    const float* iout1_b   = (const float*)d_in[34];
    const float* iout2_w   = (const float*)d_in[35];
    const float* iout2_b   = (const float*)d_in[36];
    float* out = (float*)d_out;

    float* ws = (float*)d_ws;
    size_t off = 0;
    auto alloc  = [&](size_t n)   { size_t o = off; off += (n + 63) & ~(size_t)63; return ws + o; };
    auto allocS = [&](size_t nsh) { return (short*)alloc((nsh + 1) >> 1); };

    // persistent fp32
    float* qenc   = alloc((size_t)BATCH * HID);
    float* att_ia = alloc((size_t)BATCH * KOBJ);
    float* att_ga = alloc((size_t)BATCH * NS);
    int*   tidx   = (int*)alloc((size_t)BATCH * NS);
    float* timg_f = alloc((size_t)2560 * FEAT);
    float* kw1    = alloc((size_t)BATCH * NS * NS * NK);
    float* kw2    = alloc((size_t)BATCH * NS * NS * NK);
    // persistent bf16 (hi/lo pairs for PREC3 scoring path)
    short* wih_h   = allocS((size_t)3072 * 320);  short* wih_l   = allocS((size_t)3072 * 320);
    short* whh_h   = allocS((size_t)3072 * 1024); short* whh_l   = allocS((size_t)3072 * 1024);
    short* iaimg_h = allocS((size_t)1024 * 2080); short* iaimg_l = allocS((size_t)1024 * 2080);
    short* iatxt_h = allocS((size_t)1024 * 1024); short* iatxt_l = allocS((size_t)1024 * 1024);
    short* emb_h   = allocS((size_t)3584 * 320);  short* emb_l   = allocS((size_t)3584 * 320);
    short* qenc_h  = allocS((size_t)256 * 1024);  short* qenc_l  = allocS((size_t)256 * 1024);
    // phase-reused regions
    float* R1 = alloc(12500000);   // 25.0M shorts
    float* U  = alloc(19200000);   // 38.4M shorts

    // --- phase-local views ---
    // A: GRU
    float* gi_all = R1;                          // 3584 x 3072
    float* gh     = R1 + 11010048;               // 256 x 3072
    // B: image attention
    float* improj = R1;                          // 9216 x 1024
    float* qproj  = R1 + 9437184;                // 256 x 1024
    short* img_h  = (short*)U;                   // 9216 x 2080
    short* img_l  = (short*)U + 19169280;
    short* imatt_h = (short*)U + 13189120;       // 256 x 2080 (after img dead)
    // C: graph convs
    float* Y1 = R1;                              // 2560 x 2048
    float* Y2 = R1 + 5242880;                    // 2560 x 1024
    short* gc1t_h = (short*)(R1 + 7864320);      // 2048 x 2080
    short* gc2t_h = (short*)(R1 + 7864320) + 4259840; // 1024 x 2048
    short* timg_h = (short*)U;                   // 2560 x 2080
    short* h1_h   = (short*)U + 5324800;         // 2560 x 2048
    short* h2_h   = (short*)U + 10567680;        // 2560 x 1024
    float* h2_f   = (float*)((short*)U + 20807680); // 2560 x 1024 fp32
    // D: graph attention
    float* gproj   = R1;                         // 2560 x 1024
    float* qproj2  = R1 + 2621440;               // 256 x 1024
    float* gtmp    = R1 + 2883584;               // 256 x 1024
    short* gatt_img_h = (short*)U + 13721600;    // 256 x 2080
    short* gatt_h2_h  = (short*)U + 14254080;    // 256 x 1024
    short* gcomb_h = (short*)U + 14516224;       // 256 x 1024
    short* icomb_h = (short*)U + 14778368;       // 256 x 1024
    short* hid1_h  = (short*)U + 15040512;       // 256 x 3008
    short* hid2_h  = (short*)U + 15810560;       // 256 x 3008
    short* gaw_img_h = (short*)U + 16580608;     // 1024 x 2080
    short* gaw_h2_h  = (short*)U + 18710528;     // 1024 x 1024
    short* gatxt_h   = (short*)U + 19759104;     // 1024 x 1024
    // E: output weights (into R1, after gcomb done)
    short* o1w_h  = (short*)R1;                  // 3072 x 1024
    short* io1w_h = (short*)R1 + 3145728;
    short* o2w_h  = (short*)R1 + 6291456;        // 3072 x 3008
    short* io2w_h = (short*)R1 + 15532032;

    auto NB = [](size_t n) { return (unsigned)((n + 255) / 256); };

    // ===== conversions (phase A/B weights + image) =====
    cvt_k<<<NB(983040),  256, 0, stream>>>(gru_wih, 300, 3072, 300, wih_h, wih_l, 320, 983040);
    cvt_k<<<NB(3145728), 256, 0, stream>>>(gru_whh, 1024, 3072, 1024, whh_h, whh_l, 1024, 3145728);
    cvt_k<<<NB(2129920), 256, 0, stream>>>(ia_img_w, FEAT, 1024, FEAT, iaimg_h, iaimg_l, 2080, 2129920);
    cvt_k<<<NB(1048576), 256, 0, stream>>>(ia_txt_w, 1024, 1024, 1024, iatxt_h, iatxt_l, 1024, 1048576);
    cvt_k<<<NB(19169280),256, 0, stream>>>(image, FEAT, 9216, FEAT, img_h, img_l, 2080, 19169280);
    embed_k<<<NB(1146880), 256, 0, stream>>>(question, wembed, emb_h, emb_l);
    fill0_k<<<NB(262144), 256, 0, stream>>>(qenc, 262144);
    fill0_k<<<NB(262144), 256, 0, stream>>>((float*)qenc_h, 262144);   // zeros qenc_h + qenc_l

    // ===== Phase A: GRU =====
    mg(stream, 3, 4, emb_h, emb_l, 320, wih_h, wih_l, 320, gi_all, 3072, nullptr, 0,
       gru_bih, nullptr, 0, 3584, 3072, 320, 0, 0);
    for (int t = 0; t < QLEN_; t++) {
        mg(stream, 3, 2, qenc_h, qenc_l, 1024, whh_h, whh_l, 1024, gh, 3072, nullptr, 0,
           gru_bhh, nullptr, 0, 256, 3072, 1024, 0, 0);
        gru_point_k<<<NB(262144), 256, 0, stream>>>(gi_all + (size_t)t * 3 * HID, QLEN_ * 3 * HID,
                                                    gh, qlen, qenc, qenc_h, qenc_l, t);
    }

    // ===== Phase B: image attention (scoring = PREC3) =====
    mg(stream, 3, 4, img_h, img_l, 2080, iaimg_h, iaimg_l, 2080, improj, 1024, nullptr, 0,
       ia_img_b, nullptr, 0, 9216, 1024, 2080, 0, 1);
    mg(stream, 3, 2, qenc_h, qenc_l, 1024, iatxt_h, iatxt_l, 1024, qproj, 1024, nullptr, 0,
       ia_txt_b, nullptr, 0, 256, 1024, 1024, 0, 1);
    attraw_k<<<(BATCH * KOBJ) / 4, 256, 0, stream>>>(improj, qproj, ia_att_w, ia_att_b, att_ia, KOBJ);
    softmax_k<<<1, 256, 0, stream>>>(att_ia, KOBJ);
    wsumb_k<<<NB(532480), 256, 0, stream>>>(image, FEAT, att_ia, KOBJ, imatt_h, 2080, 532480);
    mg(stream, 1, 2, imatt_h, nullptr, 2080, iaimg_h, nullptr, 2080, nullptr, 0, icomb_h, 1024,
       ia_img_b, qproj, 1024, 256, 1024, 2080, 0, 1);

    // ===== Phase C: top-k + graph convs =====
    topk_k<<<1, 256, 0, stream>>>(att_ia, tidx);
    gather_k<<<NB(5324800), 256, 0, stream>>>(image, tidx, timg_f, timg_h);
    kw_k<<<NB(25600), 256, 0, stream>>>(image, tidx, gc1_mu, gc1_sigma, gc2_mu, gc2_sigma, kw1, kw2);
    packcvt_k<<<dim3(8, 65, NK), dim3(32, 8), 0, stream>>>(gc1_w, gc1t_h, FEAT, 256, 2080);
    packcvt_k<<<dim3(4, 64, NK), dim3(32, 8), 0, stream>>>(gc2_w, gc2t_h, 2048, 128, 2048);
    mg(stream, 1, 4, timg_h, nullptr, 2080, gc1t_h, nullptr, 2080, Y1, 2048, nullptr, 0,
       nullptr, nullptr, 0, 2560, 2048, 2080, 0, 0);
    mix_k<<<NB(5242880), 256, 0, stream>>>(Y1, kw1, gc1_b, h1_h, nullptr, 256, 2048);
    mg(stream, 1, 4, h1_h, nullptr, 2048, gc2t_h, nullptr, 2048, Y2, 1024, nullptr, 0,
       nullptr, nullptr, 0, 2560, 1024, 2048, 0, 0);
    mix_k<<<NB(2621440), 256, 0, stream>>>(Y2, kw2, gc2_b, h2_h, h2_f, 128, 1024);

    // ===== Phase D: graph attention ([timg | h2], never materialized) =====
    cvt_k<<<NB(2129920), 256, 0, stream>>>(ga_img_w, FEAT + HID, 1024, FEAT, gaw_img_h, nullptr, 2080, 2129920);
    cvt_k<<<NB(1048576), 256, 0, stream>>>(ga_img_w + FEAT, FEAT + HID, 1024, HID, gaw_h2_h, nullptr, 1024, 1048576);
    cvt_k<<<NB(1048576), 256, 0, stream>>>(ga_txt_w, 1024, 1024, 1024, gatxt_h, nullptr, 1024, 1048576);
    mg(stream, 1, 4, timg_h, nullptr, 2080, gaw_img_h, nullptr, 2080, gproj, 1024, nullptr, 0,
       nullptr, nullptr, 0, 2560, 1024, 2080, 0, 0);
    mg(stream, 1, 4, h2_h, nullptr, 1024, gaw_h2_h, nullptr, 1024, gproj, 1024, nullptr, 0,
       ga_img_b, nullptr, 0, 2560, 1024, 1024, 1, 1);
    mg(stream, 1, 2, qenc_h, nullptr, 1024, gatxt_h, nullptr, 1024, qproj2, 1024, nullptr, 0,
       ga_txt_b, nullptr, 0, 256, 1024, 1024, 0, 1);
    attraw_k<<<(BATCH * NS) / 4, 256, 0, stream>>>(gproj, qproj2, ga_att_w, ga_att_b, att_ga, NS);
    softmax_k<<<1, 256, 0, stream>>>(att_ga, NS);
    wsumb_k<<<NB(532480), 256, 0, stream>>>(timg_f, FEAT, att_ga, NS, gatt_img_h, 2080, 532480);
    wsumb_k<<<NB(262144), 256, 0, stream>>>(h2_f, HID, att_ga, NS, gatt_h2_h, 1024, 262144);
    mg(stream, 1, 2, gatt_img_h, nullptr, 2080, gaw_img_h, nullptr, 2080, gtmp, 1024, nullptr, 0,
       nullptr, nullptr, 0, 256, 1024, 2080, 0, 0);
    mg(stream, 1, 2, gatt_h2_h, nullptr, 1024, gaw_h2_h, nullptr, 1024, gtmp, 1024, gcomb_h, 1024,
       ga_img_b, qproj2, 1024, 256, 1024, 1024, 1, 1);

    // ===== Phase E: output MLPs =====
    cvt_k<<<NB(3145728), 256, 0, stream>>>(out1_w, 1024, OUTN, 1024, o1w_h, nullptr, 1024, 3145728);
    cvt_k<<<NB(3145728), 256, 0, stream>>>(iout1_w, 1024, OUTN, 1024, io1w_h, nullptr, 1024, 3145728);
    cvt_k<<<NB(9240576), 256, 0, stream>>>(out2_w, OUTN, OUTN, OUTN, o2w_h, nullptr, 3008, 9240576);
    cvt_k<<<NB(9240576), 256, 0, stream>>>(iout2_w, OUTN, OUTN, OUTN, io2w_h, nullptr, 3008, 9240576);
    mg(stream, 1, 2, gcomb_h, nullptr, 1024, o1w_h, nullptr, 1024, nullptr, 0, hid1_h, 3008,
       out1_b, nullptr, 0, 256, OUTN, 1024, 0, 1);
    mg(stream, 1, 2, icomb_h, nullptr, 1024, io1w_h, nullptr, 1024, nullptr, 0, hid2_h, 3008,
       iout1_b, nullptr, 0, 256, OUTN, 1024, 0, 1);
    mg(stream, 1, 2, hid1_h, nullptr, 3008, o2w_h, nullptr, 3008, out, OUTN, nullptr, 0,
       out2_b, nullptr, 0, 256, OUTN, 3008, 0, 0);
    mg(stream, 1, 2, hid2_h, nullptr, 3008, io2w_h, nullptr, 3008, out, OUTN, nullptr, 0,
       iout2_b, nullptr, 0, 256, OUTN, 3008, 1, 0);
}